// Round 1
// baseline (221.761 us; speedup 1.0000x reference)
//
#include <hip/hip_runtime.h>

// CompositeLoss R12: d-walking restructure of loss_main.
// Theory: R11 was memory-LATENCY bound (VALUBusy 28%, HBM 21%, VGPR=40 ->
// ~2-3 outstanding f4 loads/wave; the 7 d-neighbor loads at +64KB stride
// always miss L1). Each thread now owns a 4-plane d-column of one w4 group:
// the d-neighbor comes from the previous iteration's REGISTERS (pm/pp/pt),
// so the only redundant global traffic is the one chunk-boundary plane
// (7 f4 per 4 planes) and the h-row (L1-hit: block covers 8 adjacent h).
// f4 loads per 4-voxel plane-slot: 21 -> 15.75. __launch_bounds__(256,2)
// lifts the VGPR cap so the compiler can hoist whole-plane load packets.
// W-neighbor still via __shfl_down (wv=0 kills the lane-31/63 garbage).
// Partial rows: 1024 blocks * 4 waves = 4096 rows of 16 (per-wave rows,
// no __syncthreads in loss_main). Reduction fused into ONE single-block
// kernel (was loss_mid + loss_final).
//  0:M 1:Mx(d) 2:My(h) 3:Mz(w)  4:Smae 5:Smse 6:Sbg
//  7:Sgx 8:Sgy 9:Sgz  10:Stx 11:Sty 12:Stz
#define NACC 13
#define NPAD 16
#define NBLOCKS 1024   // 2^18 threads / 256; thread = (b,dc,h,w4), 4 planes
#define NROWS 4096     // NBLOCKS * 4 waves

__device__ __forceinline__ float4 ld4(const float* p) {
    return *reinterpret_cast<const float4*>(p);
}

__global__ __launch_bounds__(256, 2) void loss_main(
    const float* __restrict__ pred, const float* __restrict__ target,
    const float* __restrict__ mask, float* __restrict__ partials)
{
    float acc[NACC];
#pragma unroll
    for (int k = 0; k < NACC; ++k) acc[k] = 0.f;

    // g = (b, dc, h, w4): w4 in lane bits -> w-shfl works as in R11
    const int g  = blockIdx.x * 256 + threadIdx.x;
    const int w4 = g & 31;
    const int h  = (g >> 5) & 127;
    const int dc = (g >> 12) & 31;   // block-uniform (bits >= 8)
    const int b  = g >> 17;          // block-uniform
    const int w  = w4 << 2;
    const int d0 = dc << 2;

    const float wv = (w4 < 31) ? 1.f : 0.f;
    const float hv = (h < 127) ? 1.f : 0.f;
    const int   oh = (h < 127) ? 128 : 0;

    const int mb0 = b * 2097152 + d0 * 16384 + h * 128 + w; // mask base
    const int pb0 = b * 6291456 + d0 * 16384 + h * 128 + w; // pred/tgt base

    // previous-plane registers (d-neighbor source)
    float4 pm;
    float4 pp[3], pt[3];   // only static (unrolled) indexing below

#pragma unroll
    for (int j = 0; j < 4; ++j) {
        const int mb = mb0 + j * 16384;
        const float4 m0  = ld4(mask + mb);
        const float4 mh  = ld4(mask + mb + oh);
        const float  m4w = __shfl_down(m0.x, 1, 64); // lane w4=31: wv=0

        const float mz0 = fminf(m0.x, m0.y), mz1 = fminf(m0.y, m0.z),
                    mz2 = fminf(m0.z, m0.w), mz3 = fminf(m0.w, m4w) * wv;
        const float my0 = fminf(m0.x, mh.x) * hv, my1 = fminf(m0.y, mh.y) * hv,
                    my2 = fminf(m0.z, mh.z) * hv, my3 = fminf(m0.w, mh.w) * hv;

        acc[0] += m0.x + m0.y + m0.z + m0.w;
        acc[2] += my0 + my1 + my2 + my3;
        acc[3] += mz0 + mz1 + mz2 + mz3;

        float mx0 = 0.f, mx1 = 0.f, mx2 = 0.f, mx3 = 0.f;
        if (j > 0) {   // d-pair (d0+j-1, d0+j); both planes interior
            mx0 = fminf(pm.x, m0.x); mx1 = fminf(pm.y, m0.y);
            mx2 = fminf(pm.z, m0.z); mx3 = fminf(pm.w, m0.w);
            acc[1] += mx0 + mx1 + mx2 + mx3;
        }

#pragma unroll
        for (int c = 0; c < 3; ++c) {
            const int pb = pb0 + j * 16384 + c * 2097152;
            const float4 p0 = ld4(pred + pb);
            const float4 t0 = ld4(target + pb);
            const float4 ph = ld4(pred + pb + oh);
            const float4 th = ld4(target + pb + oh);
            const float  p4 = __shfl_down(p0.x, 1, 64);
            const float  t4 = __shfl_down(t0.x, 1, 64);

            const float e0x = p0.x - t0.x, e0y = p0.y - t0.y,
                        e0z = p0.z - t0.z, e0w = p0.w - t0.w;
            const float e4  = p4 - t4;

            acc[4] += fabsf(e0x)*m0.x + fabsf(e0y)*m0.y
                    + fabsf(e0z)*m0.z + fabsf(e0w)*m0.w;
            acc[5] += e0x*e0x*m0.x + e0y*e0y*m0.y
                    + e0z*e0z*m0.z + e0w*e0w*m0.w;
            acc[6] += fabsf(p0.x)*(1.f-m0.x) + fabsf(p0.y)*(1.f-m0.y)
                    + fabsf(p0.z)*(1.f-m0.z) + fabsf(p0.w)*(1.f-m0.w);

            // W direction (reference dz); mz3=0 at w-boundary kills garbage
            acc[9]  += fabsf(e0y-e0x)*mz0 + fabsf(e0z-e0y)*mz1
                     + fabsf(e0w-e0z)*mz2 + fabsf(e4 -e0w)*mz3;
            acc[12] += fabsf(p0.y-p0.x)*mz0 + fabsf(p0.z-p0.y)*mz1
                     + fabsf(p0.w-p0.z)*mz2 + fabsf(p4  -p0.w)*mz3;

            // H direction (reference dy); my*=0 at h-boundary
            acc[8]  += fabsf((ph.x-th.x)-e0x)*my0 + fabsf((ph.y-th.y)-e0y)*my1
                     + fabsf((ph.z-th.z)-e0z)*my2 + fabsf((ph.w-th.w)-e0w)*my3;
            acc[11] += fabsf(ph.x-p0.x)*my0 + fabsf(ph.y-p0.y)*my1
                     + fabsf(ph.z-p0.z)*my2 + fabsf(ph.w-p0.w)*my3;

            // D direction (reference dx): prev plane from registers
            if (j > 0) {
                const float qx = pp[c].x - pt[c].x, qy = pp[c].y - pt[c].y,
                            qz = pp[c].z - pt[c].z, qw = pp[c].w - pt[c].w;
                acc[7]  += fabsf(e0x-qx)*mx0 + fabsf(e0y-qy)*mx1
                         + fabsf(e0z-qz)*mx2 + fabsf(e0w-qw)*mx3;
                acc[10] += fabsf(p0.x-pp[c].x)*mx0 + fabsf(p0.y-pp[c].y)*mx1
                         + fabsf(p0.z-pp[c].z)*mx2 + fabsf(p0.w-pp[c].w)*mx3;
            }
            pp[c] = p0; pt[c] = t0;
        }
        pm = m0;
    }

    // chunk-boundary d-pair (d0+3, d0+4); absent for dc==31 (true boundary,
    // dv=0). dc is block-uniform -> branch is non-divergent.
    if (dc < 31) {
        const float4 mN = ld4(mask + mb0 + 4 * 16384);
        const float mx0 = fminf(pm.x, mN.x), mx1 = fminf(pm.y, mN.y),
                    mx2 = fminf(pm.z, mN.z), mx3 = fminf(pm.w, mN.w);
        acc[1] += mx0 + mx1 + mx2 + mx3;
#pragma unroll
        for (int c = 0; c < 3; ++c) {
            const int pb = pb0 + 4 * 16384 + c * 2097152;
            const float4 pN = ld4(pred + pb);
            const float4 tN = ld4(target + pb);
            const float qx = pp[c].x - pt[c].x, qy = pp[c].y - pt[c].y,
                        qz = pp[c].z - pt[c].z, qw = pp[c].w - pt[c].w;
            const float nx = pN.x - tN.x, ny = pN.y - tN.y,
                        nz = pN.z - tN.z, nw = pN.w - tN.w;
            acc[7]  += fabsf(nx-qx)*mx0 + fabsf(ny-qy)*mx1
                     + fabsf(nz-qz)*mx2 + fabsf(nw-qw)*mx3;
            acc[10] += fabsf(pN.x-pp[c].x)*mx0 + fabsf(pN.y-pp[c].y)*mx1
                     + fabsf(pN.z-pp[c].z)*mx2 + fabsf(pN.w-pp[c].w)*mx3;
        }
    }

    // per-wave shuffle reduce -> own partials row; NO __syncthreads.
    const int lane = threadIdx.x & 63;
    const int wave = threadIdx.x >> 6;
    float mine = 0.f;   // lane k (<16) ends up holding total of acc[k]
#pragma unroll
    for (int k = 0; k < NACC; ++k) {
        float v = acc[k];
        for (int o = 32; o > 0; o >>= 1) v += __shfl_down(v, o, 64);
        const float tot = __shfl(v, 0, 64);
        if (lane == k) mine = tot;
    }
    if (lane < NPAD)
        partials[(blockIdx.x * 4 + wave) * NPAD + lane] = mine; // pad rows=0
}

// Fused reduction: ONE single-block kernel over 4096 rows (256 KB).
// 1024 threads; thread t serial-sums rows {t, t+1024, t+2048, t+3072},
// wave shuffle-reduce, cross-wave via LDS, thread 0 does the epilogue.
__global__ __launch_bounds__(1024) void loss_reduce(
    const float* __restrict__ partials, float* __restrict__ out)
{
    const int t    = threadIdx.x;
    const int lane = t & 63;
    const int wave = t >> 6;

    float acc[NPAD];
#pragma unroll
    for (int k = 0; k < NPAD; ++k) acc[k] = 0.f;

#pragma unroll
    for (int r = 0; r < 4; ++r) {
        const float* row = partials + (r * 1024 + t) * NPAD;
        const float4 r0 = ld4(row);      const float4 r1 = ld4(row + 4);
        const float4 r2 = ld4(row + 8);  const float4 r3 = ld4(row + 12);
        acc[0]  += r0.x; acc[1]  += r0.y; acc[2]  += r0.z; acc[3]  += r0.w;
        acc[4]  += r1.x; acc[5]  += r1.y; acc[6]  += r1.z; acc[7]  += r1.w;
        acc[8]  += r2.x; acc[9]  += r2.y; acc[10] += r2.z; acc[11] += r2.w;
        acc[12] += r3.x; acc[13] += r3.y; acc[14] += r3.z; acc[15] += r3.w;
    }

    __shared__ float red[16][NPAD];
#pragma unroll
    for (int k = 0; k < NACC; ++k) {
        float v = acc[k];
        for (int o = 32; o > 0; o >>= 1) v += __shfl_down(v, o, 64);
        if (lane == 0) red[wave][k] = v;
    }
    __syncthreads();

    if (t == 0) {
        float tot[NACC];
#pragma unroll
        for (int k = 0; k < NACC; ++k) {
            float s = 0.f;
            for (int wv2 = 0; wv2 < 16; ++wv2) s += red[wv2][k];
            tot[k] = s;
        }
        const float EPS = 1e-8f;
        const float M = tot[0], Mx = tot[1], My = tot[2], Mz = tot[3];
        float loss = (tot[4] + tot[5]) / (3.f * M + EPS);   // W_MAE=1, W_MSE=1
        loss += 0.1f   * (tot[7] / (3.f*Mx + EPS) + tot[8] / (3.f*My + EPS)
                        + tot[9] / (3.f*Mz + EPS));
        loss += 0.002f * (tot[10] / (3.f*Mx + EPS) + tot[11] / (3.f*My + EPS)
                        + tot[12] / (3.f*Mz + EPS));
        const float inv = 4194304.f - M;  // B*D*H*W - M
        loss += 0.15f * tot[6] / (3.f * inv + EPS);
        out[0] = loss;
    }
}

extern "C" void kernel_launch(void* const* d_in, const int* in_sizes, int n_in,
                              void* d_out, int out_size, void* d_ws, size_t ws_size,
                              hipStream_t stream) {
    const float* pred   = (const float*)d_in[0];
    const float* target = (const float*)d_in[1];
    const float* mask   = (const float*)d_in[2];
    float* out      = (float*)d_out;
    float* partials = (float*)d_ws;               // 4096*16 floats = 256 KiB

    loss_main<<<NBLOCKS, 256, 0, stream>>>(pred, target, mask, partials);
    loss_reduce<<<1, 1024, 0, stream>>>(partials, out);
}

// Round 2
// 209.310 us; speedup vs baseline: 1.0595x; 1.0595x over previous
//
#include <hip/hip_runtime.h>

// CompositeLoss R13: R11 body + all-loads-up-front MLP.
// R12 post-mortem: d-walk carried pm/pp/pt across a serial loop with a
// boundary tail -> allocator spilled ~640 B/thread (WRITE_SIZE 1MB->168MB,
// dur 40->118us). Reverted to the proven one-group-per-thread R11 mapping.
// R13 change: issue ALL 21 float4 loads in one straight-line block (84 VGPR
// of destinations, no cross-iteration liveness), __launch_bounds__(256,4)
// caps VGPR at 128 -> 4 waves/SIMD with ~21 loads in flight each (vs R11's
// VGPR=40 / ~3 in flight). One full load-latency exposure per thread
// instead of ~6 serialized waits. Tripwire: WRITE_SIZE must be ~1 MB; if
// it balloons, spills returned and the cap must be relaxed.
// Partial rows: 4 waves/block * 4096 blocks = 16384 rows of 16.
//  0:M 1:Mx(d) 2:My(h) 3:Mz(w)  4:Smae 5:Smse 6:Sbg
//  7:Sgx 8:Sgy 9:Sgz  10:Stx 11:Sty 12:Stz
#define NACC 13
#define NPAD 16
#define NBLOCKS 4096   // 2^20 groups / 256
#define NROWS 16384    // NBLOCKS * 4 waves

__device__ __forceinline__ float4 ld4(const float* p) {
    return *reinterpret_cast<const float4*>(p);
}

__global__ __launch_bounds__(256, 4) void loss_main(
    const float* __restrict__ pred, const float* __restrict__ target,
    const float* __restrict__ mask, float* __restrict__ partials)
{
    float acc[NACC];
#pragma unroll
    for (int k = 0; k < NACC; ++k) acc[k] = 0.f;

    // one group per thread: group = (b, d, h, w4); mapping identical to R11
    const int g  = blockIdx.x * 256 + threadIdx.x;
    const int w4 = g & 31;
    const int h  = (g >> 5) & 127;
    const int d  = (g >> 12) & 127;
    const int b  = g >> 19;
    const int w  = w4 << 2;
    const int mb  = b * 2097152 + d * 16384 + h * 128 + w; // mask index
    const int pb0 = b * 6291456 + d * 16384 + h * 128 + w; // pred/target base

    // boundary: clamp offsets in-bounds; flags zero the affected masks
    const float wv = (w4 < 31) ? 1.f : 0.f;
    const float hv = (h < 127) ? 1.f : 0.f;
    const float dv = (d < 127) ? 1.f : 0.f;
    const int oh = (h < 127) ? 128   : 0;
    const int od = (d < 127) ? 16384 : 0;

    // ---- issue ALL 21 float4 loads up front: max memory-level parallelism.
    // Straight-line liveness only (every value consumed below, nothing
    // carried across a loop) -> compiler can sink, not spill.
    const float4 m0 = ld4(mask + mb);
    const float4 mh = ld4(mask + mb + oh);
    const float4 md = ld4(mask + mb + od);
    float4 P0[3], T0[3], PH[3], TH[3], PD[3], TD[3];
#pragma unroll
    for (int c = 0; c < 3; ++c) {
        const int pb = pb0 + c * 2097152;
        P0[c] = ld4(pred + pb);
        T0[c] = ld4(target + pb);
        PD[c] = ld4(pred + pb + od);     // long-latency (L2/L3, +64KB)
        TD[c] = ld4(target + pb + od);
        PH[c] = ld4(pred + pb + oh);     // likely L1 (neighbor thread's row)
        TH[c] = ld4(target + pb + oh);
    }

    const float m4w = __shfl_down(m0.x, 1, 64);  // lane w4=31: garbage, wv=0

    // pairwise mins (binary mask -> AND); boundary flags kill clamped terms
    const float mz0 = fminf(m0.x, m0.y), mz1 = fminf(m0.y, m0.z),
                mz2 = fminf(m0.z, m0.w), mz3 = fminf(m0.w, m4w) * wv;
    const float my0 = fminf(m0.x, mh.x) * hv, my1 = fminf(m0.y, mh.y) * hv,
                my2 = fminf(m0.z, mh.z) * hv, my3 = fminf(m0.w, mh.w) * hv;
    const float mx0 = fminf(m0.x, md.x) * dv, mx1 = fminf(m0.y, md.y) * dv,
                mx2 = fminf(m0.z, md.z) * dv, mx3 = fminf(m0.w, md.w) * dv;

    acc[0] = m0.x + m0.y + m0.z + m0.w;
    acc[1] = mx0 + mx1 + mx2 + mx3;
    acc[2] = my0 + my1 + my2 + my3;
    acc[3] = mz0 + mz1 + mz2 + mz3;

#pragma unroll
    for (int c = 0; c < 3; ++c) {
        const float4 p0 = P0[c], t0 = T0[c];
        const float4 ph = PH[c], th = TH[c];
        const float4 pd = PD[c], td = TD[c];
        const float  p4 = __shfl_down(p0.x, 1, 64);  // w-neighbor from lane+1
        const float  t4 = __shfl_down(t0.x, 1, 64);

        const float e0x = p0.x - t0.x, e0y = p0.y - t0.y,
                    e0z = p0.z - t0.z, e0w = p0.w - t0.w;
        const float e4  = p4 - t4;

        acc[4] += fabsf(e0x)*m0.x + fabsf(e0y)*m0.y
                + fabsf(e0z)*m0.z + fabsf(e0w)*m0.w;
        acc[5] += e0x*e0x*m0.x + e0y*e0y*m0.y
                + e0z*e0z*m0.z + e0w*e0w*m0.w;
        acc[6] += fabsf(p0.x)*(1.f-m0.x) + fabsf(p0.y)*(1.f-m0.y)
                + fabsf(p0.z)*(1.f-m0.z) + fabsf(p0.w)*(1.f-m0.w);

        // W direction (reference dz); mz3=0 at w-boundary kills shfl garbage
        acc[9]  += fabsf(e0y-e0x)*mz0 + fabsf(e0z-e0y)*mz1
                 + fabsf(e0w-e0z)*mz2 + fabsf(e4 -e0w)*mz3;
        acc[12] += fabsf(p0.y-p0.x)*mz0 + fabsf(p0.z-p0.y)*mz1
                 + fabsf(p0.w-p0.z)*mz2 + fabsf(p4  -p0.w)*mz3;

        // H direction (reference dy); my*=0 at h-boundary
        acc[8]  += fabsf((ph.x-th.x)-e0x)*my0 + fabsf((ph.y-th.y)-e0y)*my1
                 + fabsf((ph.z-th.z)-e0z)*my2 + fabsf((ph.w-th.w)-e0w)*my3;
        acc[11] += fabsf(ph.x-p0.x)*my0 + fabsf(ph.y-p0.y)*my1
                 + fabsf(ph.z-p0.z)*my2 + fabsf(ph.w-p0.w)*my3;

        // D direction (reference dx); mx*=0 at d-boundary
        acc[7]  += fabsf((pd.x-td.x)-e0x)*mx0 + fabsf((pd.y-td.y)-e0y)*mx1
                 + fabsf((pd.z-td.z)-e0z)*mx2 + fabsf((pd.w-td.w)-e0w)*mx3;
        acc[10] += fabsf(pd.x-p0.x)*mx0 + fabsf(pd.y-p0.y)*mx1
                 + fabsf(pd.z-p0.z)*mx2 + fabsf(pd.w-p0.w)*mx3;
    }

    // per-wave shuffle reduce -> own partials row; NO __syncthreads:
    // each wave retires as soon as its own tail drains.
    const int lane = threadIdx.x & 63;
    const int wave = threadIdx.x >> 6;
    float mine = 0.f;   // lane k (<16) ends up holding total of acc[k]
#pragma unroll
    for (int k = 0; k < NACC; ++k) {
        float v = acc[k];
        for (int o = 32; o > 0; o >>= 1) v += __shfl_down(v, o, 64);
        const float tot = __shfl(v, 0, 64);
        if (lane == k) mine = tot;
    }
    if (lane < NPAD)
        partials[(blockIdx.x * 4 + wave) * NPAD + lane] = mine; // pad rows=0
}

// Fused reduction: ONE single-block kernel over 16384 rows (1 MiB).
// 1024 threads; thread t serial-sums rows {t, t+1024, ..., t+15*1024}
// (coalesced: consecutive threads read consecutive 64B rows), wave
// shuffle-reduce, cross-wave via LDS, thread 0 does the epilogue.
__global__ __launch_bounds__(1024) void loss_reduce(
    const float* __restrict__ partials, float* __restrict__ out)
{
    const int t    = threadIdx.x;
    const int lane = t & 63;
    const int wave = t >> 6;

    float acc[NPAD];
#pragma unroll
    for (int k = 0; k < NPAD; ++k) acc[k] = 0.f;

#pragma unroll
    for (int r = 0; r < 16; ++r) {
        const float* row = partials + (r * 1024 + t) * NPAD;
        const float4 r0 = ld4(row);      const float4 r1 = ld4(row + 4);
        const float4 r2 = ld4(row + 8);  const float4 r3 = ld4(row + 12);
        acc[0]  += r0.x; acc[1]  += r0.y; acc[2]  += r0.z; acc[3]  += r0.w;
        acc[4]  += r1.x; acc[5]  += r1.y; acc[6]  += r1.z; acc[7]  += r1.w;
        acc[8]  += r2.x; acc[9]  += r2.y; acc[10] += r2.z; acc[11] += r2.w;
        acc[12] += r3.x; acc[13] += r3.y; acc[14] += r3.z; acc[15] += r3.w;
    }

    __shared__ float red[16][NPAD];
#pragma unroll
    for (int k = 0; k < NACC; ++k) {
        float v = acc[k];
        for (int o = 32; o > 0; o >>= 1) v += __shfl_down(v, o, 64);
        if (lane == 0) red[wave][k] = v;
    }
    __syncthreads();

    if (t == 0) {
        float tot[NACC];
#pragma unroll
        for (int k = 0; k < NACC; ++k) {
            float s = 0.f;
            for (int wv2 = 0; wv2 < 16; ++wv2) s += red[wv2][k];
            tot[k] = s;
        }
        const float EPS = 1e-8f;
        const float M = tot[0], Mx = tot[1], My = tot[2], Mz = tot[3];
        float loss = (tot[4] + tot[5]) / (3.f * M + EPS);   // W_MAE=1, W_MSE=1
        loss += 0.1f   * (tot[7] / (3.f*Mx + EPS) + tot[8] / (3.f*My + EPS)
                        + tot[9] / (3.f*Mz + EPS));
        loss += 0.002f * (tot[10] / (3.f*Mx + EPS) + tot[11] / (3.f*My + EPS)
                        + tot[12] / (3.f*Mz + EPS));
        const float inv = 4194304.f - M;  // B*D*H*W - M
        loss += 0.15f * tot[6] / (3.f * inv + EPS);
        out[0] = loss;
    }
}

extern "C" void kernel_launch(void* const* d_in, const int* in_sizes, int n_in,
                              void* d_out, int out_size, void* d_ws, size_t ws_size,
                              hipStream_t stream) {
    const float* pred   = (const float*)d_in[0];
    const float* target = (const float*)d_in[1];
    const float* mask   = (const float*)d_in[2];
    float* out      = (float*)d_out;
    float* partials = (float*)d_ws;               // 16384*16 floats = 1 MiB

    loss_main<<<NBLOCKS, 256, 0, stream>>>(pred, target, mask, partials);
    loss_reduce<<<1, 1024, 0, stream>>>(partials, out);
}

// Round 3
// 144.871 us; speedup vs baseline: 1.5307x; 1.4448x over previous
//
#include <hip/hip_runtime.h>

// CompositeLoss R14: R13 loss_main (unchanged) + two-stage reduction.
// R13 post-mortem: fusing the reduce into ONE 1024-thread block made it
// read 1 MiB of freshly-written, XCD-scattered partials from a single CU
// -> latency-serialized at 14 GB/s, 75 us (!). Stage-1 parallelism must
// scale with the bytes: back to loss_mid (64 blocks, coalesced, 1 row per
// thread) + loss_final (1 wave over 64 rows + scalar epilogue), which was
// invisible in the R11 profile. loss_main untouched so this round yields
// clean counters for the R13 all-loads-up-front MLP change.
// Partial rows: 4 waves/block * 4096 blocks = 16384 rows of 16.
//  0:M 1:Mx(d) 2:My(h) 3:Mz(w)  4:Smae 5:Smse 6:Sbg
//  7:Sgx 8:Sgy 9:Sgz  10:Stx 11:Sty 12:Stz
#define NACC 13
#define NPAD 16
#define NBLOCKS 4096   // 2^20 groups / 256
#define NROWS 16384    // NBLOCKS * 4 waves
#define NMID 64        // 16384 / 256

__device__ __forceinline__ float4 ld4(const float* p) {
    return *reinterpret_cast<const float4*>(p);
}

__global__ __launch_bounds__(256, 4) void loss_main(
    const float* __restrict__ pred, const float* __restrict__ target,
    const float* __restrict__ mask, float* __restrict__ partials)
{
    float acc[NACC];
#pragma unroll
    for (int k = 0; k < NACC; ++k) acc[k] = 0.f;

    // one group per thread: group = (b, d, h, w4); mapping identical to R11
    const int g  = blockIdx.x * 256 + threadIdx.x;
    const int w4 = g & 31;
    const int h  = (g >> 5) & 127;
    const int d  = (g >> 12) & 127;
    const int b  = g >> 19;
    const int w  = w4 << 2;
    const int mb  = b * 2097152 + d * 16384 + h * 128 + w; // mask index
    const int pb0 = b * 6291456 + d * 16384 + h * 128 + w; // pred/target base

    // boundary: clamp offsets in-bounds; flags zero the affected masks
    const float wv = (w4 < 31) ? 1.f : 0.f;
    const float hv = (h < 127) ? 1.f : 0.f;
    const float dv = (d < 127) ? 1.f : 0.f;
    const int oh = (h < 127) ? 128   : 0;
    const int od = (d < 127) ? 16384 : 0;

    // ---- issue ALL 21 float4 loads up front: max memory-level parallelism.
    // Straight-line liveness only (every value consumed below, nothing
    // carried across a loop) -> compiler can sink, not spill.
    const float4 m0 = ld4(mask + mb);
    const float4 mh = ld4(mask + mb + oh);
    const float4 md = ld4(mask + mb + od);
    float4 P0[3], T0[3], PH[3], TH[3], PD[3], TD[3];
#pragma unroll
    for (int c = 0; c < 3; ++c) {
        const int pb = pb0 + c * 2097152;
        P0[c] = ld4(pred + pb);
        T0[c] = ld4(target + pb);
        PD[c] = ld4(pred + pb + od);     // long-latency (L2/L3, +64KB)
        TD[c] = ld4(target + pb + od);
        PH[c] = ld4(pred + pb + oh);     // likely L1 (neighbor thread's row)
        TH[c] = ld4(target + pb + oh);
    }

    const float m4w = __shfl_down(m0.x, 1, 64);  // lane w4=31: garbage, wv=0

    // pairwise mins (binary mask -> AND); boundary flags kill clamped terms
    const float mz0 = fminf(m0.x, m0.y), mz1 = fminf(m0.y, m0.z),
                mz2 = fminf(m0.z, m0.w), mz3 = fminf(m0.w, m4w) * wv;
    const float my0 = fminf(m0.x, mh.x) * hv, my1 = fminf(m0.y, mh.y) * hv,
                my2 = fminf(m0.z, mh.z) * hv, my3 = fminf(m0.w, mh.w) * hv;
    const float mx0 = fminf(m0.x, md.x) * dv, mx1 = fminf(m0.y, md.y) * dv,
                mx2 = fminf(m0.z, md.z) * dv, mx3 = fminf(m0.w, md.w) * dv;

    acc[0] = m0.x + m0.y + m0.z + m0.w;
    acc[1] = mx0 + mx1 + mx2 + mx3;
    acc[2] = my0 + my1 + my2 + my3;
    acc[3] = mz0 + mz1 + mz2 + mz3;

#pragma unroll
    for (int c = 0; c < 3; ++c) {
        const float4 p0 = P0[c], t0 = T0[c];
        const float4 ph = PH[c], th = TH[c];
        const float4 pd = PD[c], td = TD[c];
        const float  p4 = __shfl_down(p0.x, 1, 64);  // w-neighbor from lane+1
        const float  t4 = __shfl_down(t0.x, 1, 64);

        const float e0x = p0.x - t0.x, e0y = p0.y - t0.y,
                    e0z = p0.z - t0.z, e0w = p0.w - t0.w;
        const float e4  = p4 - t4;

        acc[4] += fabsf(e0x)*m0.x + fabsf(e0y)*m0.y
                + fabsf(e0z)*m0.z + fabsf(e0w)*m0.w;
        acc[5] += e0x*e0x*m0.x + e0y*e0y*m0.y
                + e0z*e0z*m0.z + e0w*e0w*m0.w;
        acc[6] += fabsf(p0.x)*(1.f-m0.x) + fabsf(p0.y)*(1.f-m0.y)
                + fabsf(p0.z)*(1.f-m0.z) + fabsf(p0.w)*(1.f-m0.w);

        // W direction (reference dz); mz3=0 at w-boundary kills shfl garbage
        acc[9]  += fabsf(e0y-e0x)*mz0 + fabsf(e0z-e0y)*mz1
                 + fabsf(e0w-e0z)*mz2 + fabsf(e4 -e0w)*mz3;
        acc[12] += fabsf(p0.y-p0.x)*mz0 + fabsf(p0.z-p0.y)*mz1
                 + fabsf(p0.w-p0.z)*mz2 + fabsf(p4  -p0.w)*mz3;

        // H direction (reference dy); my*=0 at h-boundary
        acc[8]  += fabsf((ph.x-th.x)-e0x)*my0 + fabsf((ph.y-th.y)-e0y)*my1
                 + fabsf((ph.z-th.z)-e0z)*my2 + fabsf((ph.w-th.w)-e0w)*my3;
        acc[11] += fabsf(ph.x-p0.x)*my0 + fabsf(ph.y-p0.y)*my1
                 + fabsf(ph.z-p0.z)*my2 + fabsf(ph.w-p0.w)*my3;

        // D direction (reference dx); mx*=0 at d-boundary
        acc[7]  += fabsf((pd.x-td.x)-e0x)*mx0 + fabsf((pd.y-td.y)-e0y)*mx1
                 + fabsf((pd.z-td.z)-e0z)*mx2 + fabsf((pd.w-td.w)-e0w)*mx3;
        acc[10] += fabsf(pd.x-p0.x)*mx0 + fabsf(pd.y-p0.y)*mx1
                 + fabsf(pd.z-p0.z)*mx2 + fabsf(pd.w-p0.w)*mx3;
    }

    // per-wave shuffle reduce -> own partials row; NO __syncthreads:
    // each wave retires as soon as its own tail drains.
    const int lane = threadIdx.x & 63;
    const int wave = threadIdx.x >> 6;
    float mine = 0.f;   // lane k (<16) ends up holding total of acc[k]
#pragma unroll
    for (int k = 0; k < NACC; ++k) {
        float v = acc[k];
        for (int o = 32; o > 0; o >>= 1) v += __shfl_down(v, o, 64);
        const float tot = __shfl(v, 0, 64);
        if (lane == k) mine = tot;
    }
    if (lane < NPAD)
        partials[(blockIdx.x * 4 + wave) * NPAD + lane] = mine; // pad rows=0
}

// Level 1: 64 blocks x 256 threads; thread r reads row r (4 independent
// float4), block-reduces 256 rows -> 1 row. 64 CUs share the 1 MiB read.
__global__ __launch_bounds__(256) void loss_mid(
    const float* __restrict__ partials, float* __restrict__ mid)
{
    const int r = blockIdx.x * 256 + threadIdx.x;   // exactly covers 16384
    const float* row = partials + r * NPAD;
    const float4 r0 = ld4(row);     const float4 r1 = ld4(row + 4);
    const float4 r2 = ld4(row + 8); const float4 r3 = ld4(row + 12);
    float acc[NPAD] = {r0.x, r0.y, r0.z, r0.w, r1.x, r1.y, r1.z, r1.w,
                       r2.x, r2.y, r2.z, r2.w, r3.x, r3.y, r3.z, r3.w};

    const int lane = threadIdx.x & 63;
    const int wave = threadIdx.x >> 6;
    __shared__ float red[4][NPAD];
#pragma unroll
    for (int k = 0; k < NPAD; ++k) {
        float v = acc[k];
        for (int o = 32; o > 0; o >>= 1) v += __shfl_down(v, o, 64);
        if (lane == 0) red[wave][k] = v;
    }
    __syncthreads();
    if (threadIdx.x < NPAD) {
        const int k = threadIdx.x;
        mid[blockIdx.x * NPAD + k] =
            red[0][k] + red[1][k] + red[2][k] + red[3][k];
    }
}

// Level 2: one wave; lane l reads mid row l (64 rows), shuffle-reduce,
// lane 0 does the scalar epilogue.
__global__ __launch_bounds__(64) void loss_final(
    const float* __restrict__ mid, float* __restrict__ out)
{
    const int lane = threadIdx.x;
    float acc[NPAD];
    {
        const float* row = mid + lane * NPAD;   // lane < 64 == NMID
        const float4 r0 = ld4(row);     const float4 r1 = ld4(row + 4);
        const float4 r2 = ld4(row + 8); const float4 r3 = ld4(row + 12);
        acc[0] = r0.x;  acc[1] = r0.y;  acc[2] = r0.z;  acc[3] = r0.w;
        acc[4] = r1.x;  acc[5] = r1.y;  acc[6] = r1.z;  acc[7] = r1.w;
        acc[8] = r2.x;  acc[9] = r2.y;  acc[10] = r2.z; acc[11] = r2.w;
        acc[12] = r3.x; acc[13] = r3.y; acc[14] = r3.z; acc[15] = r3.w;
    }
#pragma unroll
    for (int k = 0; k < NACC; ++k) {
        for (int o = 32; o > 0; o >>= 1) acc[k] += __shfl_down(acc[k], o, 64);
    }
    if (lane == 0) {
        const float EPS = 1e-8f;
        const float M = acc[0], Mx = acc[1], My = acc[2], Mz = acc[3];
        float loss = (acc[4] + acc[5]) / (3.f * M + EPS);   // W_MAE=1, W_MSE=1
        loss += 0.1f   * (acc[7] / (3.f*Mx + EPS) + acc[8] / (3.f*My + EPS)
                        + acc[9] / (3.f*Mz + EPS));
        loss += 0.002f * (acc[10] / (3.f*Mx + EPS) + acc[11] / (3.f*My + EPS)
                        + acc[12] / (3.f*Mz + EPS));
        const float inv = 4194304.f - M;  // B*D*H*W - M
        loss += 0.15f * acc[6] / (3.f * inv + EPS);
        out[0] = loss;
    }
}

extern "C" void kernel_launch(void* const* d_in, const int* in_sizes, int n_in,
                              void* d_out, int out_size, void* d_ws, size_t ws_size,
                              hipStream_t stream) {
    const float* pred   = (const float*)d_in[0];
    const float* target = (const float*)d_in[1];
    const float* mask   = (const float*)d_in[2];
    float* out      = (float*)d_out;
    float* partials = (float*)d_ws;                 // 16384*16 floats = 1 MiB
    float* mid      = partials + NROWS * NPAD;      // 64*16 floats

    loss_main<<<NBLOCKS, 256, 0, stream>>>(pred, target, mask, partials);
    loss_mid<<<NMID, 256, 0, stream>>>(partials, mid);
    loss_final<<<1, 64, 0, stream>>>(mid, out);
}

// Round 4
// 139.783 us; speedup vs baseline: 1.5865x; 1.0364x over previous
//
#include <hip/hip_runtime.h>

// CompositeLoss R15: R14 + sched_barrier-pinned load block.
// R14 post-mortem: all-loads-up-front at SOURCE level did nothing -- the
// machine scheduler re-sank the loads next to their uses (VGPR stayed 56,
// ~5 loads in flight/wave, 45us, VALUBusy 26%). Little's law needs ~140
// float4 in flight per CU to cover the measured 1.5 TB/s at ~375ns miss
// latency; we had ~55. Fix: __builtin_amdgcn_sched_barrier(0) between the
// 21-load block and the compute -- nothing may cross, so all loads issue
// before first use (84 f4 destinations forced live). __launch_bounds__
// (256,3) caps VGPR ~170 so the allocator has headroom (no spill).
// Tripwires: VGPR_Count must jump to ~120-160; WRITE_SIZE must stay ~1MB.
// Partial rows: 4 waves/block * 4096 blocks = 16384 rows of 16.
//  0:M 1:Mx(d) 2:My(h) 3:Mz(w)  4:Smae 5:Smse 6:Sbg
//  7:Sgx 8:Sgy 9:Sgz  10:Stx 11:Sty 12:Stz
#define NACC 13
#define NPAD 16
#define NBLOCKS 4096   // 2^20 groups / 256
#define NROWS 16384    // NBLOCKS * 4 waves
#define NMID 64        // 16384 / 256

__device__ __forceinline__ float4 ld4(const float* p) {
    return *reinterpret_cast<const float4*>(p);
}

__global__ __launch_bounds__(256, 3) void loss_main(
    const float* __restrict__ pred, const float* __restrict__ target,
    const float* __restrict__ mask, float* __restrict__ partials)
{
    float acc[NACC];
#pragma unroll
    for (int k = 0; k < NACC; ++k) acc[k] = 0.f;

    // one group per thread: group = (b, d, h, w4); mapping identical to R11
    const int g  = blockIdx.x * 256 + threadIdx.x;
    const int w4 = g & 31;
    const int h  = (g >> 5) & 127;
    const int d  = (g >> 12) & 127;
    const int b  = g >> 19;
    const int w  = w4 << 2;
    const int mb  = b * 2097152 + d * 16384 + h * 128 + w; // mask index
    const int pb0 = b * 6291456 + d * 16384 + h * 128 + w; // pred/target base

    // boundary: clamp offsets in-bounds; flags zero the affected masks
    const float wv = (w4 < 31) ? 1.f : 0.f;
    const float hv = (h < 127) ? 1.f : 0.f;
    const float dv = (d < 127) ? 1.f : 0.f;
    const int oh = (h < 127) ? 128   : 0;
    const int od = (d < 127) ? 16384 : 0;

    // ---- issue ALL 21 float4 loads, then PIN them with sched_barrier(0):
    // the scheduler may not sink any load past the barrier, so every load
    // is outstanding before the first compute waits on it.
    const float4 m0 = ld4(mask + mb);
    const float4 mh = ld4(mask + mb + oh);
    const float4 md = ld4(mask + mb + od);
    float4 P0[3], T0[3], PH[3], TH[3], PD[3], TD[3];
#pragma unroll
    for (int c = 0; c < 3; ++c) {
        const int pb = pb0 + c * 2097152;
        P0[c] = ld4(pred + pb);
        T0[c] = ld4(target + pb);
        PD[c] = ld4(pred + pb + od);     // long-latency (L2/L3, +64KB)
        TD[c] = ld4(target + pb + od);
        PH[c] = ld4(pred + pb + oh);     // likely L1 (neighbor thread's row)
        TH[c] = ld4(target + pb + oh);
    }
    __builtin_amdgcn_sched_barrier(0);   // <- loads may not sink past here

    const float m4w = __shfl_down(m0.x, 1, 64);  // lane w4=31: garbage, wv=0

    // pairwise mins (binary mask -> AND); boundary flags kill clamped terms
    const float mz0 = fminf(m0.x, m0.y), mz1 = fminf(m0.y, m0.z),
                mz2 = fminf(m0.z, m0.w), mz3 = fminf(m0.w, m4w) * wv;
    const float my0 = fminf(m0.x, mh.x) * hv, my1 = fminf(m0.y, mh.y) * hv,
                my2 = fminf(m0.z, mh.z) * hv, my3 = fminf(m0.w, mh.w) * hv;
    const float mx0 = fminf(m0.x, md.x) * dv, mx1 = fminf(m0.y, md.y) * dv,
                mx2 = fminf(m0.z, md.z) * dv, mx3 = fminf(m0.w, md.w) * dv;

    acc[0] = m0.x + m0.y + m0.z + m0.w;
    acc[1] = mx0 + mx1 + mx2 + mx3;
    acc[2] = my0 + my1 + my2 + my3;
    acc[3] = mz0 + mz1 + mz2 + mz3;

#pragma unroll
    for (int c = 0; c < 3; ++c) {
        const float4 p0 = P0[c], t0 = T0[c];
        const float4 ph = PH[c], th = TH[c];
        const float4 pd = PD[c], td = TD[c];
        const float  p4 = __shfl_down(p0.x, 1, 64);  // w-neighbor from lane+1
        const float  t4 = __shfl_down(t0.x, 1, 64);

        const float e0x = p0.x - t0.x, e0y = p0.y - t0.y,
                    e0z = p0.z - t0.z, e0w = p0.w - t0.w;
        const float e4  = p4 - t4;

        acc[4] += fabsf(e0x)*m0.x + fabsf(e0y)*m0.y
                + fabsf(e0z)*m0.z + fabsf(e0w)*m0.w;
        acc[5] += e0x*e0x*m0.x + e0y*e0y*m0.y
                + e0z*e0z*m0.z + e0w*e0w*m0.w;
        acc[6] += fabsf(p0.x)*(1.f-m0.x) + fabsf(p0.y)*(1.f-m0.y)
                + fabsf(p0.z)*(1.f-m0.z) + fabsf(p0.w)*(1.f-m0.w);

        // W direction (reference dz); mz3=0 at w-boundary kills shfl garbage
        acc[9]  += fabsf(e0y-e0x)*mz0 + fabsf(e0z-e0y)*mz1
                 + fabsf(e0w-e0z)*mz2 + fabsf(e4 -e0w)*mz3;
        acc[12] += fabsf(p0.y-p0.x)*mz0 + fabsf(p0.z-p0.y)*mz1
                 + fabsf(p0.w-p0.z)*mz2 + fabsf(p4  -p0.w)*mz3;

        // H direction (reference dy); my*=0 at h-boundary
        acc[8]  += fabsf((ph.x-th.x)-e0x)*my0 + fabsf((ph.y-th.y)-e0y)*my1
                 + fabsf((ph.z-th.z)-e0z)*my2 + fabsf((ph.w-th.w)-e0w)*my3;
        acc[11] += fabsf(ph.x-p0.x)*my0 + fabsf(ph.y-p0.y)*my1
                 + fabsf(ph.z-p0.z)*my2 + fabsf(ph.w-p0.w)*my3;

        // D direction (reference dx); mx*=0 at d-boundary
        acc[7]  += fabsf((pd.x-td.x)-e0x)*mx0 + fabsf((pd.y-td.y)-e0y)*mx1
                 + fabsf((pd.z-td.z)-e0z)*mx2 + fabsf((pd.w-td.w)-e0w)*mx3;
        acc[10] += fabsf(pd.x-p0.x)*mx0 + fabsf(pd.y-p0.y)*mx1
                 + fabsf(pd.z-p0.z)*mx2 + fabsf(pd.w-p0.w)*mx3;
    }

    // per-wave shuffle reduce -> own partials row; NO __syncthreads:
    // each wave retires as soon as its own tail drains.
    const int lane = threadIdx.x & 63;
    const int wave = threadIdx.x >> 6;
    float mine = 0.f;   // lane k (<16) ends up holding total of acc[k]
#pragma unroll
    for (int k = 0; k < NACC; ++k) {
        float v = acc[k];
        for (int o = 32; o > 0; o >>= 1) v += __shfl_down(v, o, 64);
        const float tot = __shfl(v, 0, 64);
        if (lane == k) mine = tot;
    }
    if (lane < NPAD)
        partials[(blockIdx.x * 4 + wave) * NPAD + lane] = mine; // pad rows=0
}

// Level 1: 64 blocks x 256 threads; thread r reads row r (4 independent
// float4), block-reduces 256 rows -> 1 row. 64 CUs share the 1 MiB read.
__global__ __launch_bounds__(256) void loss_mid(
    const float* __restrict__ partials, float* __restrict__ mid)
{
    const int r = blockIdx.x * 256 + threadIdx.x;   // exactly covers 16384
    const float* row = partials + r * NPAD;
    const float4 r0 = ld4(row);     const float4 r1 = ld4(row + 4);
    const float4 r2 = ld4(row + 8); const float4 r3 = ld4(row + 12);
    float acc[NPAD] = {r0.x, r0.y, r0.z, r0.w, r1.x, r1.y, r1.z, r1.w,
                       r2.x, r2.y, r2.z, r2.w, r3.x, r3.y, r3.z, r3.w};

    const int lane = threadIdx.x & 63;
    const int wave = threadIdx.x >> 6;
    __shared__ float red[4][NPAD];
#pragma unroll
    for (int k = 0; k < NPAD; ++k) {
        float v = acc[k];
        for (int o = 32; o > 0; o >>= 1) v += __shfl_down(v, o, 64);
        if (lane == 0) red[wave][k] = v;
    }
    __syncthreads();
    if (threadIdx.x < NPAD) {
        const int k = threadIdx.x;
        mid[blockIdx.x * NPAD + k] =
            red[0][k] + red[1][k] + red[2][k] + red[3][k];
    }
}

// Level 2: one wave; lane l reads mid row l (64 rows), shuffle-reduce,
// lane 0 does the scalar epilogue.
__global__ __launch_bounds__(64) void loss_final(
    const float* __restrict__ mid, float* __restrict__ out)
{
    const int lane = threadIdx.x;
    float acc[NPAD];
    {
        const float* row = mid + lane * NPAD;   // lane < 64 == NMID
        const float4 r0 = ld4(row);     const float4 r1 = ld4(row + 4);
        const float4 r2 = ld4(row + 8); const float4 r3 = ld4(row + 12);
        acc[0] = r0.x;  acc[1] = r0.y;  acc[2] = r0.z;  acc[3] = r0.w;
        acc[4] = r1.x;  acc[5] = r1.y;  acc[6] = r1.z;  acc[7] = r1.w;
        acc[8] = r2.x;  acc[9] = r2.y;  acc[10] = r2.z; acc[11] = r2.w;
        acc[12] = r3.x; acc[13] = r3.y; acc[14] = r3.z; acc[15] = r3.w;
    }
#pragma unroll
    for (int k = 0; k < NACC; ++k) {
        for (int o = 32; o > 0; o >>= 1) acc[k] += __shfl_down(acc[k], o, 64);
    }
    if (lane == 0) {
        const float EPS = 1e-8f;
        const float M = acc[0], Mx = acc[1], My = acc[2], Mz = acc[3];
        float loss = (acc[4] + acc[5]) / (3.f * M + EPS);   // W_MAE=1, W_MSE=1
        loss += 0.1f   * (acc[7] / (3.f*Mx + EPS) + acc[8] / (3.f*My + EPS)
                        + acc[9] / (3.f*Mz + EPS));
        loss += 0.002f * (acc[10] / (3.f*Mx + EPS) + acc[11] / (3.f*My + EPS)
                        + acc[12] / (3.f*Mz + EPS));
        const float inv = 4194304.f - M;  // B*D*H*W - M
        loss += 0.15f * acc[6] / (3.f * inv + EPS);
        out[0] = loss;
    }
}

extern "C" void kernel_launch(void* const* d_in, const int* in_sizes, int n_in,
                              void* d_out, int out_size, void* d_ws, size_t ws_size,
                              hipStream_t stream) {
    const float* pred   = (const float*)d_in[0];
    const float* target = (const float*)d_in[1];
    const float* mask   = (const float*)d_in[2];
    float* out      = (float*)d_out;
    float* partials = (float*)d_ws;                 // 16384*16 floats = 1 MiB
    float* mid      = partials + NROWS * NPAD;      // 64*16 floats

    loss_main<<<NBLOCKS, 256, 0, stream>>>(pred, target, mask, partials);
    loss_mid<<<NMID, 256, 0, stream>>>(partials, mid);
    loss_final<<<1, 64, 0, stream>>>(mid, out);
}